// Round 8
// baseline (315.432 us; speedup 1.0000x reference)
//
#include <hip/hip_runtime.h>
#include <hip/hip_bf16.h>
#include <cstdint>
#include <cstddef>

#define B_   64
#define T_   196
#define D_   768
#define H_   12
#define HID_ 64
#define NT_  (B_ * T_)   // 12544

typedef __attribute__((ext_vector_type(8))) __bf16 bf16x8;
typedef __attribute__((ext_vector_type(4))) float  f32x4;

typedef __attribute__((address_space(1))) const void* gas_t;
typedef __attribute__((address_space(3))) void*       las_t;

__device__ __forceinline__ float bf2f(uint16_t u) {
    uint32_t x = ((uint32_t)u) << 16;
    return __builtin_bit_cast(float, x);
}
__device__ __forceinline__ uint16_t f2bf(float f) {
    uint32_t x = __builtin_bit_cast(uint32_t, f);
    uint32_t r = (x + 0x7fffu + ((x >> 16) & 1u)) >> 16;
    return (uint16_t)r;
}
__device__ __forceinline__ __bf16 f2bfv(float f) {
    return __builtin_bit_cast(__bf16, f2bf(f));
}

// fast gate math: v_rcp_f32 (~1 ulp) instead of IEEE div expansion
__device__ __forceinline__ float sigm(float x) {
    return __builtin_amdgcn_rcpf(1.f + __expf(-x));
}
__device__ __forceinline__ float tanh_f(float x) {
    return 1.f - 2.f * __builtin_amdgcn_rcpf(1.f + __expf(2.f * x));
}

// XOR swizzle for [row][128] bf16 Act tiles (row stride 256B).
__device__ __forceinline__ int swzA(int row, int col) {
    int b = (row << 8) + (col << 1);
    b ^= (row & 7) << 4;
    return b >> 1;
}

// ---------------------------------------------------------------------------
// f32 -> bf16 bulk convert, float4 vectorized, grid-stride.
// ---------------------------------------------------------------------------
__global__ __launch_bounds__(256)
void f32_to_bf16_k(const float* __restrict__ in, uint16_t* __restrict__ out, int n4)
{
    int i = blockIdx.x * 256 + threadIdx.x;
    const int stride = gridDim.x * 256;
    for (; i < n4; i += stride) {
        float4 v = ((const float4*)in)[i];
        ushort4 o;
        o.x = f2bf(v.x); o.y = f2bf(v.y); o.z = f2bf(v.z); o.w = f2bf(v.w);
        ((ushort4*)out)[i] = o;
    }
}

// ---------------------------------------------------------------------------
// m97-structure MFMA NT-GEMM: C[n][m] = sum_k A[n,k]*B[m,k] + bias[m]
// (unchanged from R7)
// ---------------------------------------------------------------------------
template<int KDIM, bool OUT_BF16>
__global__ __launch_bounds__(256)
void gemm_nt_gl(const uint16_t* __restrict__ A, const uint16_t* __restrict__ Bw,
                const float* __restrict__ bias, void* __restrict__ Cout, int Mtot)
{
    constexpr int NK = KDIM / 32;
    __shared__ uint16_t smA[2][128 * 32];
    __shared__ uint16_t smB[2][128 * 32];

    const int tid = threadIdx.x, lane = tid & 63, wv = tid >> 6;
    const int n0 = blockIdx.x * 128, m0 = blockIdx.y * 128;
    const int wr = wv >> 1, wc = wv & 1;
    const int fr = lane & 15;
    const int fk8 = (lane >> 4) * 8;

    const int sr = lane >> 2;
    const int sc = (lane & 3) * 8;

    auto stage = [&](int buf, int k0) {
#pragma unroll
        for (int i = 0; i < 2; ++i) {
            const int r0 = 16 * wv + 64 * i;
            const uint16_t* ga = A  + (size_t)(n0 + r0 + sr) * KDIM + k0 + sc;
            const uint16_t* gb = Bw + (size_t)(m0 + r0 + sr) * KDIM + k0 + sc;
            __builtin_amdgcn_global_load_lds((gas_t)ga, (las_t)&smA[buf][r0 * 32], 16, 0, 0);
            __builtin_amdgcn_global_load_lds((gas_t)gb, (las_t)&smB[buf][r0 * 32], 16, 0, 0);
        }
    };

    f32x4 acc[4][4];
#pragma unroll
    for (int i = 0; i < 4; ++i)
#pragma unroll
        for (int j = 0; j < 4; ++j) acc[i][j] = (f32x4){0.f, 0.f, 0.f, 0.f};

    stage(0, 0);

    for (int kt = 0; kt < NK; ++kt) {
        const int buf = kt & 1;
        __syncthreads();
        if (kt + 1 < NK) stage(buf ^ 1, 32 * (kt + 1));

        bf16x8 af[4], bfg[4];
#pragma unroll
        for (int i = 0; i < 4; ++i)
            af[i] = *(const bf16x8*)&smA[buf][(64 * wr + 16 * i + fr) * 32 + fk8];
#pragma unroll
        for (int j = 0; j < 4; ++j)
            bfg[j] = *(const bf16x8*)&smB[buf][(64 * wc + 16 * j + fr) * 32 + fk8];
#pragma unroll
        for (int i = 0; i < 4; ++i)
#pragma unroll
            for (int j = 0; j < 4; ++j)
                acc[i][j] = __builtin_amdgcn_mfma_f32_16x16x32_bf16(af[i], bfg[j], acc[i][j], 0, 0, 0);
    }

    float biasj[4];
#pragma unroll
    for (int j = 0; j < 4; ++j) biasj[j] = bias[m0 + 64 * wc + 16 * j + fr];

#pragma unroll
    for (int i = 0; i < 4; ++i) {
#pragma unroll
        for (int r = 0; r < 4; ++r) {
            const int n = n0 + 64 * wr + 16 * i + (lane >> 4) * 4 + r;
#pragma unroll
            for (int j = 0; j < 4; ++j) {
                const int m = m0 + 64 * wc + 16 * j + fr;
                const float v = acc[i][j][r] + biasj[j];
                if constexpr (OUT_BF16)
                    ((uint16_t*)Cout)[(size_t)n * Mtot + m] = f2bf(v);
                else
                    ((float*)Cout)[(size_t)n * Mtot + m] = v;
            }
        }
    }
}

// ---------------------------------------------------------------------------
// K2 (MFMA): 96 blocks = 24 chains x 4 batch-tiles of 16. 256 thr = 4 waves.
// R8: raw s_barrier with lgkmcnt(0) ONLY (no vmcnt drain). __syncthreads'
// implicit vmcnt(0) was forcing every step to wait for the y global-store to
// retire to L2 (~200-400 cyc/step). LDS visibility needs only lgkmcnt(0);
// the x-load's register dep is hardware-enforced at its use.
// ---------------------------------------------------------------------------
__global__ __launch_bounds__(256) __attribute__((amdgpu_waves_per_eu(1)))
void lstm_rec_mfma(const uint16_t* __restrict__ xp,     // [NT][768] bf16
                   const float* __restrict__ Wih_f, const float* __restrict__ Whh_f,
                   const float* __restrict__ bih_f, const float* __restrict__ bhh_f,
                   const float* __restrict__ Wih_r, const float* __restrict__ Whh_r,
                   const float* __restrict__ bih_r, const float* __restrict__ bhh_r,
                   uint16_t* __restrict__ y)            // [NT][1536] bf16
{
    const int blk   = blockIdx.x;        // 0..95
    const int b0    = (blk & 3) * 16;
    const int chain = blk >> 2;          // 0..23
    const int head  = chain % H_;
    const int dir   = chain / H_;
    const int tid   = threadIdx.x;       // 0..255
    const int lane  = tid & 63;
    const int q     = tid >> 6;          // wave = hid group 0..3

    const float* WihP = (dir ? Wih_r : Wih_f) + (size_t)head * 256 * 64;
    const float* WhhP = (dir ? Whh_r : Whh_f) + (size_t)head * 256 * 64;
    const float* bihP = (dir ? bih_r : bih_f) + head * 256;
    const float* bhhP = (dir ? bhh_r : bhh_f) + head * 256;

    __shared__ uint16_t Act[2][16 * 128];   // double-buffered, swizzled

    const int fr = lane & 15;
    const int fk = (lane >> 4) << 3;     // 0,8,16,24

    // ---- preload W fragments: wfrag[gi][kk] (64 VGPRs, pinned) ----
    bf16x8 wfrag[4][4];
#pragma unroll
    for (int gi = 0; gi < 4; ++gi) {
        const int row = 16 * q + 64 * gi + fr;
#pragma unroll
        for (int kk = 0; kk < 4; ++kk) {
            const int k0 = 32 * kk + fk;
            const float* src = (k0 < 64) ? (WihP + row * 64 + k0)
                                         : (WhhP + row * 64 + (k0 - 64));
            float4 aa = *(const float4*)(src);
            float4 bb = *(const float4*)(src + 4);
            bf16x8 w;
            w[0] = f2bfv(aa.x); w[1] = f2bfv(aa.y); w[2] = f2bfv(aa.z); w[3] = f2bfv(aa.w);
            w[4] = f2bfv(bb.x); w[5] = f2bfv(bb.y); w[6] = f2bfv(bb.z); w[7] = f2bfv(bb.w);
            wfrag[gi][kk] = w;
        }
    }
#pragma unroll
    for (int gi = 0; gi < 4; ++gi)
#pragma unroll
        for (int kk = 0; kk < 4; ++kk)
            asm volatile("" : "+v"(wfrag[gi][kk]));

    f32x4 binit[4];
#pragma unroll
    for (int gi = 0; gi < 4; ++gi) {
#pragma unroll
        for (int r = 0; r < 4; ++r) {
            const int row = 16 * q + 64 * gi + (lane >> 4) * 4 + r;
            binit[gi][r] = bihP[row] + bhhP[row];
        }
    }

    const int tstep = dir ? -1 : 1;
    const int t0    = dir ? (T_ - 1) : 0;

    // ---- init Act[0]: h = 0, x = x(t0). thread t: batch=t>>4, d0=(t&15)*4
    const int batch = tid >> 4;
    const int d0    = (tid & 15) * 4;
    {
        uint2 z; z.x = 0; z.y = 0;
        *(uint2*)&Act[0][swzA(batch, 64 + d0)] = z;
        uint2 xv = *(const uint2*)(xp + ((size_t)(b0 + batch) * T_ + t0) * D_ + head * 64 + d0);
        *(uint2*)&Act[0][swzA(batch, d0)] = xv;
    }
    __syncthreads();

    const uint16_t* xptr = xp + ((size_t)(b0 + batch) * T_ + t0) * D_ + head * 64 + d0;
    uint16_t* yptr = y + ((size_t)(b0 + fr) * T_ + t0) * 1536 + dir * 768 + head * 64
                       + 16 * q + ((lane >> 4) << 2);
    const ptrdiff_t xstride = (ptrdiff_t)tstep * D_;
    const ptrdiff_t ystride = (ptrdiff_t)tstep * 1536;

    float cst[4] = {0.f, 0.f, 0.f, 0.f};

    for (int s = 0; s < T_; ++s) {
        // (a) prefetch next x into regs (hides under MFMA+gates)
        uint2 xstage; xstage.x = 0; xstage.y = 0;
        if (s + 1 < T_) { xptr += xstride; xstage = *(const uint2*)xptr; }

        const uint16_t* A0 = Act[s & 1];
        uint16_t*       A1 = Act[(s + 1) & 1];

        // (b) MFMA over K=128
        f32x4 acc[4];
#pragma unroll
        for (int gi = 0; gi < 4; ++gi) acc[gi] = binit[gi];
#pragma unroll
        for (int kk = 0; kk < 4; ++kk) {
            bf16x8 afr = *(const bf16x8*)&A0[swzA(fr, 32 * kk + fk)];
#pragma unroll
            for (int gi = 0; gi < 4; ++gi)
                acc[gi] = __builtin_amdgcn_mfma_f32_16x16x32_bf16(wfrag[gi][kk], afr, acc[gi], 0, 0, 0);
        }

        // (c) gates + cell update, in-register
        ushort4 hpack;
#pragma unroll
        for (int r = 0; r < 4; ++r) {
            const float i_ = sigm(acc[0][r]);
            const float f_ = sigm(acc[1][r]);
            const float g_ = tanh_f(acc[2][r]);
            const float o_ = sigm(acc[3][r]);
            const float c  = f_ * cst[r] + i_ * g_;
            cst[r] = c;
            const float h = o_ * tanh_f(c);
            ((unsigned short*)&hpack)[r] = f2bf(h);
        }

        // (d) write h(t) and x(t+1) into the OTHER buffer
        *(ushort4*)&A1[swzA(fr, 64 + 16 * q + ((lane >> 4) << 2))] = hpack;
        if (s + 1 < T_) *(uint2*)&A1[swzA(batch, d0)] = xstage;

        // (e) y store: vmem, never drained inside the loop
        *(ushort4*)yptr = hpack;
        yptr += ystride;

        // (f) raw barrier: LDS-only wait, NO vmcnt drain
        asm volatile("s_waitcnt lgkmcnt(0)" ::: "memory");
        __builtin_amdgcn_s_barrier();
        __builtin_amdgcn_sched_barrier(0);
    }
}

// ---------------------------------------------------------------------------
extern "C" void kernel_launch(void* const* d_in, const int* in_sizes, int n_in,
                              void* d_out, int out_size, void* d_ws, size_t ws_size,
                              hipStream_t stream) {
    const float* x      = (const float*)d_in[0];
    const float* pre_W  = (const float*)d_in[1];
    const float* pre_b  = (const float*)d_in[2];
    const float* Wih_f  = (const float*)d_in[3];
    const float* Whh_f  = (const float*)d_in[4];
    const float* bih_f  = (const float*)d_in[5];
    const float* bhh_f  = (const float*)d_in[6];
    const float* Wih_r  = (const float*)d_in[7];
    const float* Whh_r  = (const float*)d_in[8];
    const float* bih_r  = (const float*)d_in[9];
    const float* bhh_r  = (const float*)d_in[10];
    const float* proj_W = (const float*)d_in[11];
    const float* proj_b = (const float*)d_in[12];
    float* out = (float*)d_out;

    uint16_t* xp      = (uint16_t*)d_ws;                  // [NT][768]  19.3 MB
    uint16_t* y       = xp + (size_t)NT_ * D_;            // [NT][1536] 38.5 MB
    uint16_t* preWbf  = y + (size_t)NT_ * 1536;           // 768*768    1.2 MB
    uint16_t* projWbf = preWbf + (size_t)D_ * D_;         // 768*1536   2.4 MB
    uint16_t* xbf     = y;   // aliased: x-bf16 lives in y region until lstm runs

    f32_to_bf16_k<<<256, 256, 0, stream>>>(pre_W, preWbf, D_ * D_ / 4);
    f32_to_bf16_k<<<256, 256, 0, stream>>>(proj_W, projWbf, D_ * 1536 / 4);
    f32_to_bf16_k<<<2048, 256, 0, stream>>>(x, xbf, NT_ * D_ / 4);

    dim3 g1(NT_ / 128, D_ / 128);   // (98, 6)
    gemm_nt_gl<768, true><<<g1, 256, 0, stream>>>(xbf, preWbf, pre_b, xp, D_);

    lstm_rec_mfma<<<96, 256, 0, stream>>>(xp, Wih_f, Whh_f, bih_f, bhh_f,
                                          Wih_r, Whh_r, bih_r, bhh_r, y);

    dim3 g3(NT_ / 128, D_ / 128);   // (98, 6)
    gemm_nt_gl<1536, false><<<g3, 256, 0, stream>>>(y, projWbf, proj_b, out, D_);
}